// Round 1
// baseline (66.631 us; speedup 1.0000x reference)
//
#include <hip/hip_runtime.h>

// RMLoss: per 32-elem segment s, over all 496 pairs (i<j):
//   loss[s] = -(1/496) * sum [ log_sigmoid(x_i - x_j) + 0.0005*(x_i^2 - x_j^2) ]
// One wave (64 lanes) per segment; lanes 0..31 hold x; pairs decoded from a
// compile-time table and broadcast via __shfl (ds_bpermute). No LDS.

constexpr int NPAIR = 496;  // 32*31/2

struct PairTab { unsigned short v[512]; };
constexpr PairTab make_tab() {
    PairTab t{};
    int p = 0;
    for (int i = 0; i < 32; ++i)
        for (int j = i + 1; j < 32; ++j)
            t.v[p++] = (unsigned short)(i | (j << 8));
    while (p < 512) t.v[p++] = 0;  // padding: decodes to (0,0), masked out
    return t;
}
__constant__ PairTab TAB = make_tab();

__global__ __launch_bounds__(256) void rmloss_kernel(
        const float* __restrict__ logits, float* __restrict__ out, int n_seg) {
    const int lane = threadIdx.x & 63;
    const int wave = threadIdx.x >> 6;
    const int seg  = blockIdx.x * 4 + wave;
    if (seg >= n_seg) return;

    // lanes 0..31 hold the segment's values
    float x = 0.0f;
    if (lane < 32) x = logits[seg * 32 + lane];

    float acc = 0.0f;
#pragma unroll
    for (int it = 0; it < 8; ++it) {
        const int p = it * 64 + lane;
        const bool valid = (p < NPAIR);
        const int pc = valid ? p : 0;
        const unsigned short pk = TAB.v[pc];
        const int i = pk & 0xff;
        const int j = pk >> 8;
        const float xi = __shfl(x, i, 64);
        const float xj = __shfl(x, j, 64);
        const float t = xi - xj;
        // stable log_sigmoid(t) = min(t,0) - log(1 + exp(-|t|))
        const float ls = fminf(t, 0.0f) - __logf(1.0f + __expf(-fabsf(t)));
        const float term = ls + 0.0005f * (xi * xi - xj * xj);
        acc += valid ? term : 0.0f;
    }

    // wave-wide butterfly reduction (64 lanes)
#pragma unroll
    for (int off = 32; off > 0; off >>= 1)
        acc += __shfl_xor(acc, off, 64);

    if (lane == 0) out[seg] = -acc * (1.0f / 496.0f);
}

extern "C" void kernel_launch(void* const* d_in, const int* in_sizes, int n_in,
                              void* d_out, int out_size, void* d_ws, size_t ws_size,
                              hipStream_t stream) {
    const float* logits = (const float*)d_in[0];
    // k_lens is arange(S+1)*K; only its length matters: n_seg = len-1
    const int n_seg = in_sizes[1] - 1;
    float* out = (float*)d_out;
    const int blocks = (n_seg + 3) / 4;  // 4 waves (segments) per 256-thread block
    rmloss_kernel<<<blocks, 256, 0, stream>>>(logits, out, n_seg);
}

// Round 2
// 63.007 us; speedup vs baseline: 1.0575x; 1.0575x over previous
//
#include <hip/hip_runtime.h>

// RMLoss: per 32-elem segment s, loss[s] = -(1/496) * sum_{i<j} [ log_sigmoid(x_i-x_j)
//                                                + 0.0005*(x_i^2 - x_j^2) ]
// Key simplifications:
//  * beta term:  sum_{i<j}(x_i^2 - x_j^2) = sum_k (31-2k) x_k^2   (O(K), hoisted)
//  * log_sigmoid(t) = -softplus(-t); inputs ~N(0,1) so |t|<~15 -> naive
//    log2(1+exp2(-t*log2e)) is overflow-safe: ONE exp + ONE log per pair.
//  * pair indices pre-baked as bpermute byte-addresses, lane-major: one 16B
//    dwordx4 per lane up front, zero in-loop memory ops.
//  * pad pairs (496..511) decode to (0,0): contribute exactly log2(2)=1 each
//    to the accumulator -> subtract 16*ln2 once; no masking anywhere.

struct PairTab { unsigned short v[64][8]; };  // [lane][iter], lo byte = i*4, hi byte = j*4
constexpr PairTab make_tab() {
    PairTab t{};
    unsigned short tmp[512] = {};
    int p = 0;
    for (int i = 0; i < 32; ++i)
        for (int j = i + 1; j < 32; ++j)
            tmp[p++] = (unsigned short)((i * 4) | ((j * 4) << 8));
    for (; p < 512; ++p) tmp[p] = 0;  // pads -> pair (0,0)
    for (int it = 0; it < 8; ++it)
        for (int lane = 0; lane < 64; ++lane)
            t.v[lane][it] = tmp[it * 64 + lane];
    return t;
}
__constant__ PairTab TAB = make_tab();

__device__ __forceinline__ float bperm(int byteaddr, float v) {
    return __int_as_float(__builtin_amdgcn_ds_bpermute(byteaddr, __float_as_int(v)));
}

#if __has_builtin(__builtin_amdgcn_exp2f)
#define FAST_EXP2(x) __builtin_amdgcn_exp2f(x)
#else
#define FAST_EXP2(x) exp2f(x)
#endif
#if __has_builtin(__builtin_amdgcn_logf)
#define FAST_LOG2(x) __builtin_amdgcn_logf(x)  // v_log_f32 computes log2
#else
#define FAST_LOG2(x) log2f(x)
#endif

__global__ __launch_bounds__(256) void rmloss_kernel(
        const float* __restrict__ logits, float* __restrict__ out, int n_seg) {
    const int lane = threadIdx.x & 63;
    const int seg  = blockIdx.x * 4 + (threadIdx.x >> 6);
    if (seg >= n_seg) return;

    // lanes 0..31 hold the segment's values
    float x = 0.0f;
    if (lane < 32) x = logits[(size_t)seg * 32 + lane];

    // all 8 iterations' pair addresses in one coalesced 16B load
    const uint4 tw = *reinterpret_cast<const uint4*>(&TAB.v[lane][0]);
    const unsigned int wds[4] = {tw.x, tw.y, tw.z, tw.w};

    constexpr float LOG2E = 1.4426950408889634f;
    constexpr float LN2   = 0.6931471805599453f;

    float acc = 0.0f;  // sum of log2(1 + exp2(-t*log2e)) = softplus(-t)/ln2
#pragma unroll
    for (int it = 0; it < 8; ++it) {
        const unsigned int w  = wds[it >> 1];
        const unsigned int pk = (it & 1) ? (w >> 16) : (w & 0xffffu);
        const int ai = (int)(pk & 0xffu);
        const int aj = (int)((pk >> 8) & 0xffu);
        const float xi = bperm(ai, x);
        const float xj = bperm(aj, x);
        const float t  = xi - xj;
        const float e  = FAST_EXP2(t * -LOG2E);
        acc += FAST_LOG2(1.0f + e);
    }

    // per-lane combine: ln2*acc = sum softplus(-t) = sum -log_sigmoid(t)
    // beta part: -0.0005 * (31-2*lane) * x^2   (lanes>=32 have x=0)
    const float c = (float)(31 - 2 * lane);
    float r = LN2 * acc - 0.0005f * c * x * x;

    // 64-lane butterfly reduction
#pragma unroll
    for (int off = 32; off; off >>= 1) r += __shfl_xor(r, off, 64);

    if (lane == 0) out[seg] = (r - 16.0f * LN2) * (1.0f / 496.0f);
}

extern "C" void kernel_launch(void* const* d_in, const int* in_sizes, int n_in,
                              void* d_out, int out_size, void* d_ws, size_t ws_size,
                              hipStream_t stream) {
    const float* logits = (const float*)d_in[0];
    const int n_seg = in_sizes[1] - 1;  // k_lens has n_seg+1 entries
    float* out = (float*)d_out;
    const int blocks = (n_seg + 3) / 4;  // 4 waves (segments) per 256-thread block
    rmloss_kernel<<<blocks, 256, 0, stream>>>(logits, out, n_seg);
}

// Round 3
// 61.831 us; speedup vs baseline: 1.0776x; 1.0190x over previous
//
#include <hip/hip_runtime.h>

// RMLoss: per 32-elem segment s, loss[s] = (1/496) * sum_{i<j} [ softplus(x_j-x_i)
//                                                - 0.0005*(x_i^2 - x_j^2) ]
// (= -mean(log_sigmoid(x_i-x_j) + 0.0005*(x_i^2-x_j^2)))
//
// Structure (R3): TWO segments per wave — lanes 0..31 = seg A, lanes 32..63 =
// seg B. Each half computes its 496 pairs over 16 iterations x 32 lanes
// (512 slots, 16 pads -> exactly 1.0 each in log2 domain, subtracted once).
//  * x pre-scaled: y = x*log2e, so exp(-(xi-xj)) = exp2(yj-yi): no per-pair mul.
//  * beta term hoisted: sum_{i<j}(xi^2-xj^2) = sum_k (31-2k) xk^2.
//  * pair indices as bpermute byte addrs (upper half +128 baked in), stored
//    byte-planar: one bfe per index, two dwordx4 loads total per lane.
//  * 64-lane coalesced input load, 5-step half-wave butterfly reduction,
//    lanes 0 and 32 store. 1024-thread blocks -> 1024 grid blocks.

constexpr int K = 32;
constexpr int ITERS = 16;  // 512 pair-slots per half, 496 real + 16 pads

struct alignas(16) Tab {
    unsigned int A[64][4];  // byte-planar i-addresses: iter it in word it>>2, byte it&3
    unsigned int B[64][4];  // byte-planar j-addresses
};
constexpr Tab make_tab() {
    Tab t{};
    unsigned char ai[512] = {}, aj[512] = {};
    int p = 0;
    for (int i = 0; i < K; ++i)
        for (int j = i + 1; j < K; ++j) { ai[p] = (unsigned char)(i * 4); aj[p] = (unsigned char)(j * 4); ++p; }
    // slots 496..511 stay (0,0): pad -> yi==yj -> log2(1+1)=1 exactly
    for (int it = 0; it < ITERS; ++it)
        for (int l = 0; l < 32; ++l) {
            const int s = it * 32 + l;
            for (int half = 0; half < 2; ++half) {
                const int lane = l + 32 * half;
                const unsigned int a = ai[s] + 128u * half;  // upper half reads lanes 32..63
                const unsigned int b = aj[s] + 128u * half;
                t.A[lane][it >> 2] |= a << ((it & 3) * 8);
                t.B[lane][it >> 2] |= b << ((it & 3) * 8);
            }
        }
    return t;
}
__constant__ Tab TAB = make_tab();

__device__ __forceinline__ float bperm(int byteaddr, float v) {
    return __int_as_float(__builtin_amdgcn_ds_bpermute(byteaddr, __float_as_int(v)));
}

#if __has_builtin(__builtin_amdgcn_exp2f)
#define FAST_EXP2(x) __builtin_amdgcn_exp2f(x)
#else
#define FAST_EXP2(x) exp2f(x)
#endif
#if __has_builtin(__builtin_amdgcn_logf)
#define FAST_LOG2(x) __builtin_amdgcn_logf(x)  // v_log_f32 = log2
#else
#define FAST_LOG2(x) log2f(x)
#endif

__global__ __launch_bounds__(1024) void rmloss_kernel(
        const float* __restrict__ logits, float* __restrict__ out, int n_seg) {
    const int lane = threadIdx.x & 63;
    const int wave = blockIdx.x * 16 + (threadIdx.x >> 6);  // 16 waves/block
    const int seg0 = wave * 2;                              // segs seg0, seg0+1
    if (seg0 >= n_seg) return;

    // coalesced: wave's 64 lanes load segs seg0..seg0+1 contiguously
    const long long gidx = (long long)wave * 64 + lane;
    float x = 0.0f;
    if (gidx < (long long)n_seg * K) x = logits[gidx];

    constexpr float LOG2E = 1.4426950408889634f;
    constexpr float LN2   = 0.6931471805599453f;
    const float y = x * LOG2E;

    const uint4 wa = *reinterpret_cast<const uint4*>(&TAB.A[lane][0]);
    const uint4 wb = *reinterpret_cast<const uint4*>(&TAB.B[lane][0]);
    const unsigned int Aw[4] = {wa.x, wa.y, wa.z, wa.w};
    const unsigned int Bw[4] = {wb.x, wb.y, wb.z, wb.w};

    float acc = 0.0f;  // sum over pairs of log2(1 + exp2(yj - yi)) = softplus(xj-xi)/ln2
#pragma unroll
    for (int it = 0; it < ITERS; ++it) {
        const int w = it >> 2, sh = (it & 3) * 8;
        const int ai = (int)((Aw[w] >> sh) & 0xffu);
        const int aj = (int)((Bw[w] >> sh) & 0xffu);
        const float yi = bperm(ai, y);
        const float yj = bperm(aj, y);
        acc += FAST_LOG2(1.0f + FAST_EXP2(yj - yi));
    }

    // per-lane: remove 16 pads (1.0 each, spread as 16/32=0.5 per lane),
    // beta part uses original x: -0.0005*(31-2k)*x^2
    const int k = lane & 31;
    float r = LN2 * (acc - 0.5f) - 0.0005f * (float)(31 - 2 * k) * x * x;

    // 32-lane (half-wave) butterfly reduction
#pragma unroll
    for (int off = 16; off; off >>= 1) r += __shfl_xor(r, off, 64);

    if ((lane & 31) == 0) {
        const int seg = seg0 + (lane >> 5);
        if (seg < n_seg) out[seg] = r * (1.0f / 496.0f);
    }
}

extern "C" void kernel_launch(void* const* d_in, const int* in_sizes, int n_in,
                              void* d_out, int out_size, void* d_ws, size_t ws_size,
                              hipStream_t stream) {
    const float* logits = (const float*)d_in[0];
    const int n_seg = in_sizes[1] - 1;  // k_lens has n_seg+1 entries
    float* out = (float*)d_out;
    const int segs_per_block = 32;      // 16 waves x 2 segs
    const int blocks = (n_seg + segs_per_block - 1) / segs_per_block;
    rmloss_kernel<<<blocks, 1024, 0, stream>>>(logits, out, n_seg);
}